// Round 1
// baseline (2527.394 us; speedup 1.0000x reference)
//
#include <hip/hip_runtime.h>
#include <hip/hip_bf16.h>
#include <stdint.h>

// CortexBlock: QKV proj (bf16 MFMA GEMM) -> fast-weight scan (fp32, 1 wave per
// (b,h) chain) -> output proj (bf16 MFMA GEMM, fp32 out).
// Constants from the reference:
#define D_MODEL   1024
#define N_HEADS   16
#define D_HEAD    64
#define SEQ_T     2048
#define BATCH     4
#define DECAY_F   0.95f
#define ALPHA_MAX_F 0.05f
#define BETA_F    0.01f

typedef unsigned short u16;
typedef __bf16 bf16x8 __attribute__((ext_vector_type(8)));
typedef float  f32x4  __attribute__((ext_vector_type(4)));

// ---- helpers ---------------------------------------------------------------
__device__ __forceinline__ u16 f2bf(float x) {  // round-to-nearest-even f32->bf16
  unsigned u = __float_as_uint(x);
  u += 0x7fffu + ((u >> 16) & 1u);
  return (u16)(u >> 16);
}
__device__ __forceinline__ unsigned pk2(float a, float b) {
  return (unsigned)f2bf(a) | ((unsigned)f2bf(b) << 16);
}
__device__ __forceinline__ void bf8_to_f32(uint4 u, float* f) {
  f[0] = __uint_as_float(u.x << 16); f[1] = __uint_as_float(u.x & 0xffff0000u);
  f[2] = __uint_as_float(u.y << 16); f[3] = __uint_as_float(u.y & 0xffff0000u);
  f[4] = __uint_as_float(u.z << 16); f[5] = __uint_as_float(u.z & 0xffff0000u);
  f[6] = __uint_as_float(u.w << 16); f[7] = __uint_as_float(u.w & 0xffff0000u);
}

// ---- cast fp32 -> bf16 -----------------------------------------------------
__global__ __launch_bounds__(256) void cast_x_kernel(const float* __restrict__ src,
                                                     u16* __restrict__ dst) {
  int i = blockIdx.x * 256 + threadIdx.x;  // one float4 per thread
  float4 v = ((const float4*)src)[i];
  uint2 o; o.x = pk2(v.x, v.y); o.y = pk2(v.z, v.w);
  ((uint2*)dst)[i] = o;
}

__global__ __launch_bounds__(256) void cast_w_kernel(const float* __restrict__ wq,
                                                     const float* __restrict__ wk,
                                                     const float* __restrict__ wv,
                                                     const float* __restrict__ wo,
                                                     u16* __restrict__ dst) {
  int i = blockIdx.x * 256 + threadIdx.x;        // float4 index into 4*2^20 elems
  int which = i >> 18;                           // 2^18 float4s per matrix (uniform per block)
  const float* srcs[4] = {wq, wk, wv, wo};
  float4 v = ((const float4*)srcs[which])[i & 0x3ffff];
  uint2 o; o.x = pk2(v.x, v.y); o.y = pk2(v.z, v.w);
  ((uint2*)dst)[i] = o;
}

// ---- alpha = min(sigmoid(x@Wa^T + ba) * m_gate * a_scale, 0.05)  (fp32) ----
__global__ __launch_bounds__(256) void alpha_kernel(const float* __restrict__ X,
                                                    const float* __restrict__ Wa,
                                                    const float* __restrict__ ba,
                                                    const float* __restrict__ m_gate,
                                                    const float* __restrict__ a_scale,
                                                    float* __restrict__ alpha) {
  int m = blockIdx.x * 16 + (threadIdx.x >> 4);  // row in [0, 8192)
  int h = threadIdx.x & 15;
  const float4* x4 = (const float4*)(X + (size_t)m * D_MODEL);
  const float4* w4 = (const float4*)(Wa + (size_t)h * D_MODEL);
  float acc = 0.f;
  #pragma unroll 4
  for (int i = 0; i < D_MODEL / 4; ++i) {
    float4 a = x4[i], b = w4[i];
    acc += a.x * b.x + a.y * b.y + a.z * b.z + a.w * b.w;
  }
  float s = 1.f / (1.f + __expf(-(acc + ba[h])));
  float al = s * m_gate[m] * a_scale[(size_t)m * N_HEADS + h];
  alpha[(size_t)m * N_HEADS + h] = fminf(al, ALPHA_MAX_F);
}

// ---- bf16 MFMA GEMM: C[M,N] = A[M,K] * B[N,K]^T ----------------------------
// 128x128 tile, 4 waves (2x2 of 64x64), BK=32, mfma_f32_16x16x32_bf16.
// LDS rows padded to 40 bf16 (80B = 20 banks -> <=2-way conflict, free).
template <bool STORE_BF16>
__global__ __launch_bounds__(256) void gemm_bt_kernel(const u16* __restrict__ A,
                                                      const u16* __restrict__ B,
                                                      void* __restrict__ Cptr,
                                                      int M, int N, int K) {
  __shared__ u16 As[128][40];
  __shared__ u16 Bs[128][40];
  const int tid  = threadIdx.x;
  const int lane = tid & 63;
  const int wave = tid >> 6;
  const int wm = (wave >> 1) * 64;
  const int wn = (wave & 1) * 64;
  const int bm = blockIdx.y * 128;
  const int bn = blockIdx.x * 128;
  const int lr = tid >> 2;            // loader row 0..63
  const int lc = (tid & 3) * 8;       // loader col {0,8,16,24}
  const int quad = lane >> 4;
  const int l16  = lane & 15;

  const u16* Ap0 = A + (size_t)(bm + lr) * K + lc;
  const u16* Ap1 = A + (size_t)(bm + lr + 64) * K + lc;
  const u16* Bp0 = B + (size_t)(bn + lr) * K + lc;
  const u16* Bp1 = B + (size_t)(bn + lr + 64) * K + lc;

  f32x4 acc[4][4];
  #pragma unroll
  for (int i = 0; i < 4; ++i)
    #pragma unroll
    for (int j = 0; j < 4; ++j) acc[i][j] = (f32x4){0.f, 0.f, 0.f, 0.f};

  uint4 a0 = *(const uint4*)Ap0;
  uint4 a1 = *(const uint4*)Ap1;
  uint4 b0 = *(const uint4*)Bp0;
  uint4 b1 = *(const uint4*)Bp1;

  for (int k0 = 0; k0 < K; k0 += 32) {
    __syncthreads();
    *(uint4*)(&As[lr][lc])      = a0;
    *(uint4*)(&As[lr + 64][lc]) = a1;
    *(uint4*)(&Bs[lr][lc])      = b0;
    *(uint4*)(&Bs[lr + 64][lc]) = b1;
    __syncthreads();
    if (k0 + 32 < K) {  // prefetch next K-chunk while MFMAs run
      a0 = *(const uint4*)(Ap0 + k0 + 32);
      a1 = *(const uint4*)(Ap1 + k0 + 32);
      b0 = *(const uint4*)(Bp0 + k0 + 32);
      b1 = *(const uint4*)(Bp1 + k0 + 32);
    }
    bf16x8 af[4], bfr[4];
    #pragma unroll
    for (int i = 0; i < 4; ++i)
      af[i] = *(const bf16x8*)(&As[wm + i * 16 + l16][quad * 8]);
    #pragma unroll
    for (int j = 0; j < 4; ++j)
      bfr[j] = *(const bf16x8*)(&Bs[wn + j * 16 + l16][quad * 8]);
    #pragma unroll
    for (int i = 0; i < 4; ++i)
      #pragma unroll
      for (int j = 0; j < 4; ++j)
        acc[i][j] = __builtin_amdgcn_mfma_f32_16x16x32_bf16(af[i], bfr[j], acc[i][j], 0, 0, 0);
  }

  // epilogue: C/D layout col=lane&15, row=quad*4+reg
  #pragma unroll
  for (int i = 0; i < 4; ++i) {
    #pragma unroll
    for (int j = 0; j < 4; ++j) {
      #pragma unroll
      for (int e = 0; e < 4; ++e) {
        int row = bm + wm + i * 16 + quad * 4 + e;
        int col = bn + wn + j * 16 + l16;
        if (STORE_BF16)
          ((u16*)Cptr)[(size_t)row * N + col] = f2bf(acc[i][j][e]);
        else
          ((float*)Cptr)[(size_t)row * N + col] = acc[i][j][e];
      }
    }
  }
}

// ---- fast-weight scan ------------------------------------------------------
// One wave per (b,h) chain. Lane layout: g = lane>>3 owns d in [g*8,g*8+8),
// p = lane&7 owns r in {p, p+8}. U[d][r],V[r][d] live in registers (16 each).
// ku reduce over g: shfl_xor 8/16/32; k_fast reduce over p: shfl_xor 1/2/4.
__global__ __launch_bounds__(64) void scan_kernel(const u16* __restrict__ QKV,   // [B*T][3072] q|k|v
                                                  const float* __restrict__ Alpha, // [B*T][16]
                                                  u16* __restrict__ Y) {           // [B*T][1024]
  const int b = blockIdx.x >> 4;
  const int h = blockIdx.x & 15;
  const int lane = threadIdx.x;
  const int g = lane >> 3;
  const int p = lane & 7;

  float U0[8], U1[8], V0[8], V1[8];
  #pragma unroll
  for (int i = 0; i < 8; ++i) { U0[i] = 0.f; U1[i] = 0.f; V0[i] = 0.f; V1[i] = 0.f; }

  const int rowstride = 3 * D_MODEL;
  const u16* qp = QKV + (size_t)b * SEQ_T * rowstride + h * D_HEAD + g * 8;
  const u16* kp = qp + D_MODEL;
  const u16* vp = qp + 2 * D_MODEL;
  const float* ap = Alpha + (size_t)b * SEQ_T * N_HEADS + h;
  u16* yp = Y + (size_t)b * SEQ_T * D_MODEL + h * D_HEAD + g * 8;

  uint4 qu = *(const uint4*)qp;
  uint4 ku = *(const uint4*)kp;
  uint4 vu = *(const uint4*)vp;
  float an = *ap;

  for (int t = 0; t < SEQ_T; ++t) {
    float q[8], k[8], v[8];
    bf8_to_f32(qu, q); bf8_to_f32(ku, k); bf8_to_f32(vu, v);
    const float a = an;
    if (t + 1 < SEQ_T) {  // prefetch next step
      size_t off = (size_t)(t + 1) * rowstride;
      qu = *(const uint4*)(qp + off);
      ku = *(const uint4*)(kp + off);
      vu = *(const uint4*)(vp + off);
      an = ap[(size_t)(t + 1) * N_HEADS];
    }
    // ku[r] = k . (DECAY*U_prev)[:,r]  for r = p, p+8
    float pk0 = 0.f, pk1 = 0.f;
    #pragma unroll
    for (int i = 0; i < 8; ++i) {
      pk0 = fmaf(k[i], U0[i], pk0);
      pk1 = fmaf(k[i], U1[i], pk1);
    }
    #pragma unroll
    for (int m = 8; m <= 32; m <<= 1) {
      pk0 += __shfl_xor(pk0, m);
      pk1 += __shfl_xor(pk1, m);
    }
    const float s0 = a * DECAY_F * pk0;   // s = a*ku (with decay folded in)
    const float s1 = a * DECAY_F * pk1;
    // U = DECAY*U + s*k ; V = DECAY*V + s*v ; then X -= BETA*clip(X,-1,1)
    float c[8];
    #pragma unroll
    for (int i = 0; i < 8; ++i) {
      float u0 = fmaf(DECAY_F, U0[i], s0 * k[i]);
      float u1 = fmaf(DECAY_F, U1[i], s1 * k[i]);
      u0 = fmaf(fminf(fmaxf(u0, -1.f), 1.f), -BETA_F, u0);
      u1 = fmaf(fminf(fmaxf(u1, -1.f), 1.f), -BETA_F, u1);
      float w0 = fmaf(DECAY_F, V0[i], s0 * v[i]);
      float w1 = fmaf(DECAY_F, V1[i], s1 * v[i]);
      w0 = fmaf(fminf(fmaxf(w0, -1.f), 1.f), -BETA_F, w0);
      w1 = fmaf(fminf(fmaxf(w1, -1.f), 1.f), -BETA_F, w1);
      U0[i] = u0; U1[i] = u1; V0[i] = w0; V1[i] = w1;
      c[i] = u0 * w0 + u1 * w1;            // k_fast partial (this lane's 2 r's)
    }
    #pragma unroll
    for (int m = 1; m <= 4; m <<= 1) {
      #pragma unroll
      for (int i = 0; i < 8; ++i) c[i] += __shfl_xor(c[i], m);
    }
    // scores (q/sqrt(Dh)) . k  and  . k_fast ; reduce over g
    float ss = 0.f, sf = 0.f;
    #pragma unroll
    for (int i = 0; i < 8; ++i) {
      ss = fmaf(q[i], k[i], ss);
      sf = fmaf(q[i], c[i], sf);
    }
    #pragma unroll
    for (int m = 8; m <= 32; m <<= 1) {
      ss += __shfl_xor(ss, m);
      sf += __shfl_xor(sf, m);
    }
    ss *= 0.125f; sf *= 0.125f;
    // 2-way softmax (mix_logit adds equally to both logits -> cancels)
    const float mx = fmaxf(ss, sf);
    const float e0 = __expf(ss - mx);
    const float e1 = __expf(sf - mx);
    const float inv = 1.f / (e0 + e1);
    const float m0 = e0 * inv, m1 = e1 * inv;
    if (p == 0) {  // lanes 0,8,...,56 cover d=0..63, coalesced 16B stores
      float y[8];
      #pragma unroll
      for (int i = 0; i < 8; ++i) y[i] = m0 * v[i] + m1 * c[i];
      uint4 o;
      o.x = pk2(y[0], y[1]); o.y = pk2(y[2], y[3]);
      o.z = pk2(y[4], y[5]); o.w = pk2(y[6], y[7]);
      *(uint4*)(yp + (size_t)t * D_MODEL) = o;
    }
  }
}

// ---- launch ----------------------------------------------------------------
extern "C" void kernel_launch(void* const* d_in, const int* in_sizes, int n_in,
                              void* d_out, int out_size, void* d_ws, size_t ws_size,
                              hipStream_t stream) {
  const float* hs      = (const float*)d_in[0];
  const float* m_gate  = (const float*)d_in[1];
  const float* a_scale = (const float*)d_in[2];
  const float* Wq      = (const float*)d_in[3];
  const float* Wk      = (const float*)d_in[4];
  const float* Wv      = (const float*)d_in[5];
  const float* Wo      = (const float*)d_in[6];
  const float* Wa      = (const float*)d_in[7];
  const float* ba      = (const float*)d_in[8];
  // d_in[9] mix_logit: cancels in the 2-way softmax, unused.

  const int M = BATCH * SEQ_T;  // 8192
  char* ws = (char*)d_ws;
  u16*  Xb   = (u16*)ws;                                       // [8192][1024] bf16  (16 MB)
  u16*  Wb   = (u16*)(ws + (16u << 20));                       // [4][1024][1024] bf16 packed q,k,v,o (8 MB)
  u16*  QKVb = (u16*)(ws + (16u << 20) + (8u << 20));          // [8192][3072] bf16 (48 MB)
  float* Alph = (float*)(ws + (16u << 20) + (8u << 20) + 50331648u);  // [8192][16] f32
  u16*  Yb   = (u16*)((char*)Alph + 524288u);                  // [8192][1024] bf16 (16 MB)
  float* out = (float*)d_out;

  cast_x_kernel<<<8192, 256, 0, stream>>>(hs, Xb);
  cast_w_kernel<<<4096, 256, 0, stream>>>(Wq, Wk, Wv, Wo, Wb);
  alpha_kernel<<<512, 256, 0, stream>>>(hs, Wa, ba, m_gate, a_scale, Alph);
  gemm_bt_kernel<true><<<dim3(24, 64), 256, 0, stream>>>(Xb, Wb, QKVb, M, 3 * D_MODEL, D_MODEL);
  scan_kernel<<<BATCH * N_HEADS, 64, 0, stream>>>(QKVb, Alph, Yb);
  gemm_bt_kernel<false><<<dim3(8, 64), 256, 0, stream>>>(Yb, Wb + 3u * 1048576u, out, M, D_MODEL, D_MODEL);
}

// Round 2
// 214.403 us; speedup vs baseline: 11.7881x; 11.7881x over previous
//
#include <hip/hip_runtime.h>
#include <hip/hip_bf16.h>
#include <stdint.h>

// CortexBlock — structural simplification: the reference's fast-weight state
// U,V starts at 0 and its update is multiplicative in the state (ku = k.(0.95 U)
// = 0 -> U,V stay exactly 0, clip/beta preserve 0). Hence k_fast == 0,
// score_fast == 0, mix_logit cancels in the 2-way softmax, and:
//   y[b,t,h,:] = sigmoid((q_h . k_h)/8) * v_h ;  out = y @ Wo^T
// alpha / m_gate / alpha_scale / Wa / ba / mix_logit are dead inputs.
#define D_MODEL   1024
#define N_HEADS   16
#define D_HEAD    64
#define SEQ_T     2048
#define BATCH     4

typedef unsigned short u16;
typedef __bf16 bf16x8 __attribute__((ext_vector_type(8)));
typedef float  f32x4  __attribute__((ext_vector_type(4)));

// ---- helpers ---------------------------------------------------------------
__device__ __forceinline__ u16 f2bf(float x) {  // round-to-nearest-even f32->bf16
  unsigned u = __float_as_uint(x);
  u += 0x7fffu + ((u >> 16) & 1u);
  return (u16)(u >> 16);
}
__device__ __forceinline__ unsigned pk2(float a, float b) {
  return (unsigned)f2bf(a) | ((unsigned)f2bf(b) << 16);
}
__device__ __forceinline__ void bf8_to_f32(uint4 u, float* f) {
  f[0] = __uint_as_float(u.x << 16); f[1] = __uint_as_float(u.x & 0xffff0000u);
  f[2] = __uint_as_float(u.y << 16); f[3] = __uint_as_float(u.y & 0xffff0000u);
  f[4] = __uint_as_float(u.z << 16); f[5] = __uint_as_float(u.z & 0xffff0000u);
  f[6] = __uint_as_float(u.w << 16); f[7] = __uint_as_float(u.w & 0xffff0000u);
}

// ---- cast fp32 -> bf16 -----------------------------------------------------
__global__ __launch_bounds__(256) void cast_x_kernel(const float* __restrict__ src,
                                                     u16* __restrict__ dst) {
  int i = blockIdx.x * 256 + threadIdx.x;  // one float4 per thread
  float4 v = ((const float4*)src)[i];
  uint2 o; o.x = pk2(v.x, v.y); o.y = pk2(v.z, v.w);
  ((uint2*)dst)[i] = o;
}

__global__ __launch_bounds__(256) void cast_w_kernel(const float* __restrict__ wq,
                                                     const float* __restrict__ wk,
                                                     const float* __restrict__ wv,
                                                     const float* __restrict__ wo,
                                                     u16* __restrict__ dst) {
  int i = blockIdx.x * 256 + threadIdx.x;        // float4 index into 4*2^20 elems
  int which = i >> 18;                           // 2^18 float4s per matrix (uniform per block)
  const float* srcs[4] = {wq, wk, wv, wo};
  float4 v = ((const float4*)srcs[which])[i & 0x3ffff];
  uint2 o; o.x = pk2(v.x, v.y); o.y = pk2(v.z, v.w);
  ((uint2*)dst)[i] = o;
}

// ---- bf16 MFMA GEMM: C[M,N] = A[M,K] * B[N,K]^T ----------------------------
// 128x128 tile, 4 waves (2x2 of 64x64), BK=32, mfma_f32_16x16x32_bf16.
// LDS rows padded to 40 bf16 (80B = 20 banks -> <=2-way conflict, free).
template <bool STORE_BF16>
__global__ __launch_bounds__(256) void gemm_bt_kernel(const u16* __restrict__ A,
                                                      const u16* __restrict__ B,
                                                      void* __restrict__ Cptr,
                                                      int M, int N, int K) {
  __shared__ u16 As[128][40];
  __shared__ u16 Bs[128][40];
  const int tid  = threadIdx.x;
  const int lane = tid & 63;
  const int wave = tid >> 6;
  const int wm = (wave >> 1) * 64;
  const int wn = (wave & 1) * 64;
  const int bm = blockIdx.y * 128;
  const int bn = blockIdx.x * 128;
  const int lr = tid >> 2;            // loader row 0..63
  const int lc = (tid & 3) * 8;       // loader col {0,8,16,24}
  const int quad = lane >> 4;
  const int l16  = lane & 15;

  const u16* Ap0 = A + (size_t)(bm + lr) * K + lc;
  const u16* Ap1 = A + (size_t)(bm + lr + 64) * K + lc;
  const u16* Bp0 = B + (size_t)(bn + lr) * K + lc;
  const u16* Bp1 = B + (size_t)(bn + lr + 64) * K + lc;

  f32x4 acc[4][4];
  #pragma unroll
  for (int i = 0; i < 4; ++i)
    #pragma unroll
    for (int j = 0; j < 4; ++j) acc[i][j] = (f32x4){0.f, 0.f, 0.f, 0.f};

  uint4 a0 = *(const uint4*)Ap0;
  uint4 a1 = *(const uint4*)Ap1;
  uint4 b0 = *(const uint4*)Bp0;
  uint4 b1 = *(const uint4*)Bp1;

  for (int k0 = 0; k0 < K; k0 += 32) {
    __syncthreads();
    *(uint4*)(&As[lr][lc])      = a0;
    *(uint4*)(&As[lr + 64][lc]) = a1;
    *(uint4*)(&Bs[lr][lc])      = b0;
    *(uint4*)(&Bs[lr + 64][lc]) = b1;
    __syncthreads();
    if (k0 + 32 < K) {  // prefetch next K-chunk while MFMAs run
      a0 = *(const uint4*)(Ap0 + k0 + 32);
      a1 = *(const uint4*)(Ap1 + k0 + 32);
      b0 = *(const uint4*)(Bp0 + k0 + 32);
      b1 = *(const uint4*)(Bp1 + k0 + 32);
    }
    bf16x8 af[4], bfr[4];
    #pragma unroll
    for (int i = 0; i < 4; ++i)
      af[i] = *(const bf16x8*)(&As[wm + i * 16 + l16][quad * 8]);
    #pragma unroll
    for (int j = 0; j < 4; ++j)
      bfr[j] = *(const bf16x8*)(&Bs[wn + j * 16 + l16][quad * 8]);
    #pragma unroll
    for (int i = 0; i < 4; ++i)
      #pragma unroll
      for (int j = 0; j < 4; ++j)
        acc[i][j] = __builtin_amdgcn_mfma_f32_16x16x32_bf16(af[i], bfr[j], acc[i][j], 0, 0, 0);
  }

  // epilogue: C/D layout col=lane&15, row=quad*4+reg
  #pragma unroll
  for (int i = 0; i < 4; ++i) {
    #pragma unroll
    for (int j = 0; j < 4; ++j) {
      #pragma unroll
      for (int e = 0; e < 4; ++e) {
        int row = bm + wm + i * 16 + quad * 4 + e;
        int col = bn + wn + j * 16 + l16;
        if (STORE_BF16)
          ((u16*)Cptr)[(size_t)row * N + col] = f2bf(acc[i][j][e]);
        else
          ((float*)Cptr)[(size_t)row * N + col] = acc[i][j][e];
      }
    }
  }
}

// ---- mix: y[row,h,:] = sigmoid(dot(q_h,k_h)/8) * v_h -----------------------
// 8 lanes per (row, head); dot over 64 dims = 8/lane + shfl_xor {1,2,4}.
__global__ __launch_bounds__(256) void mix_kernel(const u16* __restrict__ QKV,  // [8192][3072]
                                                  u16* __restrict__ Y) {        // [8192][1024]
  int tid = blockIdx.x * 256 + threadIdx.x;  // 8192 rows * 128 threads/row
  int row = tid >> 7;
  int sub = tid & 127;
  int h  = sub >> 3;
  int dl = sub & 7;
  const u16* base = QKV + (size_t)row * (3 * D_MODEL) + h * D_HEAD + dl * 8;
  uint4 qu = *(const uint4*)base;
  uint4 ku = *(const uint4*)(base + D_MODEL);
  uint4 vu = *(const uint4*)(base + 2 * D_MODEL);
  float q[8], k[8], v[8];
  bf8_to_f32(qu, q); bf8_to_f32(ku, k); bf8_to_f32(vu, v);
  float s = 0.f;
  #pragma unroll
  for (int i = 0; i < 8; ++i) s = fmaf(q[i], k[i], s);
  s += __shfl_xor(s, 1);
  s += __shfl_xor(s, 2);
  s += __shfl_xor(s, 4);
  s *= 0.125f;                          // 1/sqrt(64)
  const float m0 = 1.f / (1.f + __expf(-s));
  uint4 o;
  o.x = pk2(m0 * v[0], m0 * v[1]);
  o.y = pk2(m0 * v[2], m0 * v[3]);
  o.z = pk2(m0 * v[4], m0 * v[5]);
  o.w = pk2(m0 * v[6], m0 * v[7]);
  *(uint4*)(Y + (size_t)row * D_MODEL + h * D_HEAD + dl * 8) = o;
}

// ---- launch ----------------------------------------------------------------
extern "C" void kernel_launch(void* const* d_in, const int* in_sizes, int n_in,
                              void* d_out, int out_size, void* d_ws, size_t ws_size,
                              hipStream_t stream) {
  const float* hs = (const float*)d_in[0];
  const float* Wq = (const float*)d_in[3];
  const float* Wk = (const float*)d_in[4];
  const float* Wv = (const float*)d_in[5];
  const float* Wo = (const float*)d_in[6];
  // d_in[1,2,7,8,9] (m_gate, alpha_scale, Wa, ba, mix_logit) are dead: the
  // fast-weight state is identically zero (see header comment).

  const int M = BATCH * SEQ_T;  // 8192
  char* ws = (char*)d_ws;
  u16* Xb   = (u16*)ws;                               // [8192][1024] bf16 (16 MB)
  u16* Wb   = (u16*)(ws + (16u << 20));               // [4][1024][1024] bf16 q,k,v,o (8 MB)
  u16* QKVb = (u16*)(ws + (24u << 20));               // [8192][3072] bf16 (48 MB)
  u16* Yb   = (u16*)(ws + (72u << 20));               // [8192][1024] bf16 (16 MB)
  float* out = (float*)d_out;

  cast_x_kernel<<<8192, 256, 0, stream>>>(hs, Xb);
  cast_w_kernel<<<4096, 256, 0, stream>>>(Wq, Wk, Wv, Wo, Wb);
  gemm_bt_kernel<true><<<dim3(24, 64), 256, 0, stream>>>(Xb, Wb, QKVb, M, 3 * D_MODEL, D_MODEL);
  mix_kernel<<<4096, 256, 0, stream>>>(QKVb, Yb);
  gemm_bt_kernel<false><<<dim3(8, 64), 256, 0, stream>>>(Yb, Wb + 3u * 1048576u, out, M, D_MODEL, D_MODEL);
}